// Round 1
// baseline (269.236 us; speedup 1.0000x reference)
//
#include <hip/hip_runtime.h>

// x: (16, 10, 512, 512) fp32. out: (16, 8, 512, 512) fp32.
// Per pixel: mag = sqrt(x[8]^2 + x[9]^2); out[c] = (c == argmax(x[0..7])) ? mag : 0.
// Pure streaming kernel: 167.8 MB read + 134.2 MB write, HBM-bound floor ~48 us.

constexpr int HW   = 512 * 512;      // pixels per (b, c) plane
constexpr int HW4  = HW / 4;         // float4s per plane = 65536
constexpr int B    = 16;
constexpr int CIN  = 10;
constexpr int COUT = 8;

__global__ __launch_bounds__(256) void HistogramLayer_52776558133573_kernel(
    const float* __restrict__ x, float* __restrict__ out) {
    unsigned tid = blockIdx.x * blockDim.x + threadIdx.x;   // 0 .. 16*65536-1, exact fit
    unsigned b   = tid >> 16;          // / HW4
    unsigned hw4 = tid & (HW4 - 1);    // % HW4

    const float4* xb = (const float4*)(x + (size_t)b * CIN * HW) + hw4;
    float4*       ob = (float4*)(out + (size_t)b * COUT * HW) + hw4;

    // argmax over channels 0..7 (strict > => first-max, matches jnp.argmax)
    float4 best = xb[0];
    int ix = 0, iy = 0, iz = 0, iw = 0;
#pragma unroll
    for (int c = 1; c < COUT; ++c) {
        float4 v = xb[(size_t)c * HW4];
        if (v.x > best.x) { best.x = v.x; ix = c; }
        if (v.y > best.y) { best.y = v.y; iy = c; }
        if (v.z > best.z) { best.z = v.z; iz = c; }
        if (v.w > best.w) { best.w = v.w; iw = c; }
    }

    float4 g0 = xb[8 * (size_t)HW4];
    float4 g1 = xb[9 * (size_t)HW4];
    float4 mag;
    mag.x = sqrtf(g0.x * g0.x + g1.x * g1.x);
    mag.y = sqrtf(g0.y * g0.y + g1.y * g1.y);
    mag.z = sqrtf(g0.z * g0.z + g1.z * g1.z);
    mag.w = sqrtf(g0.w * g0.w + g1.w * g1.w);

#pragma unroll
    for (int c = 0; c < COUT; ++c) {
        float4 o;
        o.x = (ix == c) ? mag.x : 0.0f;
        o.y = (iy == c) ? mag.y : 0.0f;
        o.z = (iz == c) ? mag.z : 0.0f;
        o.w = (iw == c) ? mag.w : 0.0f;
        ob[(size_t)c * HW4] = o;
    }
}

extern "C" void kernel_launch(void* const* d_in, const int* in_sizes, int n_in,
                              void* d_out, int out_size, void* d_ws, size_t ws_size,
                              hipStream_t stream) {
    const float* x = (const float*)d_in[0];
    float* out = (float*)d_out;
    const int total_f4 = B * HW4;               // 1,048,576 threads
    const int block = 256;
    const int grid = total_f4 / block;          // 4096, exact
    HistogramLayer_52776558133573_kernel<<<grid, block, 0, stream>>>(x, out);
}